// Round 3
// baseline (350.269 us; speedup 1.0000x reference)
//
#include <hip/hip_runtime.h>
#include <stdint.h>

typedef __bf16 bf16x8 __attribute__((ext_vector_type(8)));
typedef float f32x4 __attribute__((ext_vector_type(4)));

#define EPS 1e-5f

__device__ __forceinline__ float b2f(unsigned short u) {
    union { unsigned int i; float f; } c; c.i = ((unsigned int)u) << 16; return c.f;
}
__device__ __forceinline__ unsigned short f2b(float f) {
    union { float f; unsigned int i; } c; c.f = f;
    unsigned int i = c.i;
    return (unsigned short)((i + 0x7FFFu + ((i >> 16) & 1u)) >> 16);
}

// ---- dtype detector: decode linear_w's first 256 halfwords as bf16.
// bf16 N(0,0.02) data -> ~0 implausible; fp32 data -> ~half implausible.
__global__ void k_detect(const void* lw, int* flag) {
    if (threadIdx.x == 0 && blockIdx.x == 0) {
        const unsigned short* p = (const unsigned short*)lw;
        int bad = 0;
        for (int i = 0; i < 256; i++) {
            float a = fabsf(b2f(p[i]));
            if (!(a <= 100.0f) || (a != 0.0f && a < 1e-20f)) bad++;
        }
        *flag = (bad > 32) ? 1 : 0;   // 1 => inputs are fp32
    }
}

__global__ void k_zero(float* __restrict__ p, int n) {
    int i = blockIdx.x * 256 + threadIdx.x;
    if (i < n) p[i] = 0.0f;
}

__device__ __forceinline__ unsigned short cvt_elem(const void* src, size_t i, int df) {
    return df ? f2b(((const float*)src)[i]) : ((const unsigned short*)src)[i];
}

// Canonicalize params to bf16: wt1 = lw^T [256][512]; rwb = rw [512][256];
// vec = {lb(256), g1(256), b1(512..), rb, ga, ba} packed.
__global__ void k_params(const void* lw, const void* rw,
                         const void* lb, const void* g1, const void* b1,
                         const void* rb, const void* ga, const void* ba,
                         const int* __restrict__ flag,
                         unsigned short* __restrict__ wt1,
                         unsigned short* __restrict__ rwb,
                         unsigned short* __restrict__ vec) {
    const int df = *flag;
    int gid = blockIdx.x * 256 + threadIdx.x;
    if (gid < 131072) {
        int k = gid >> 8, n = gid & 255;
        wt1[n * 512 + k] = cvt_elem(lw, gid, df);
    } else if (gid < 262144) {
        int j = gid - 131072;
        rwb[j] = cvt_elem(rw, j, df);
    } else if (gid < 264448) {
        int j = gid - 262144;
        if (j < 256)       vec[j] = cvt_elem(lb, j, df);
        else if (j < 512)  vec[j] = cvt_elem(g1, j - 256, df);
        else if (j < 768)  vec[j] = cvt_elem(b1, j - 512, df);
        else if (j < 1280) vec[j] = cvt_elem(rb, j - 768, df);
        else if (j < 1792) vec[j] = cvt_elem(ga, j - 1280, df);
        else               vec[j] = cvt_elem(ba, j - 1792, df);
    }
}

// per-row LN stats of x2 (row length 256); one wave per row
__global__ __launch_bounds__(256) void k_stats(const void* __restrict__ x2v,
                                               const int* __restrict__ flag,
                                               float2* __restrict__ stats) {
    const int df = *flag;
    int t = threadIdx.x, lane = t & 63, w = t >> 6;
    size_t row = (size_t)blockIdx.x * 4 + w;
    float v0, v1, v2, v3;
    if (df) {
        float4 f = *(const float4*)((const float*)x2v + row * 256 + lane * 4);
        v0 = f.x; v1 = f.y; v2 = f.z; v3 = f.w;
    } else {
        ushort4 u = *(const ushort4*)((const unsigned short*)x2v + row * 256 + lane * 4);
        v0 = b2f(u.x); v1 = b2f(u.y); v2 = b2f(u.z); v3 = b2f(u.w);
    }
    float s = v0 + v1 + v2 + v3;
    float q = v0 * v0 + v1 * v1 + v2 * v2 + v3 * v3;
#pragma unroll
    for (int msk = 1; msk < 64; msk <<= 1) {
        s += __shfl_xor(s, msk, 64);
        q += __shfl_xor(q, msk, 64);
    }
    float mn = s * (1.0f / 256.0f);
    float rstd = rsqrtf(q * (1.0f / 256.0f) - mn * mn + EPS);
    if (lane == 0) stats[row] = make_float2(mn, rstd);
}

// ctxraw[b,h,d,e] = sum_m q[d,m]*E[e,m], n2=LN(x2) applied on the fly.
// grid 512 = (b,h)(64) x chunk(8 of 512 tokens); 256 thr
__global__ __launch_bounds__(256) void k_ctx(const void* __restrict__ x2v,
                                             const float2* __restrict__ stats,
                                             const unsigned short* __restrict__ vec,
                                             const int* __restrict__ flag,
                                             float* __restrict__ ctxraw) {
    __shared__ float E[64 * 33];
    __shared__ float Q[64 * 33];
    __shared__ float qinv[64];
    __shared__ float gs[32], bs[32];
    const int df = *flag;
    int bh = blockIdx.x >> 3;
    int b = bh >> 3, h = bh & 7;
    int ch = blockIdx.x & 7;
    int t = threadIdx.x;
    if (t < 32) { gs[t] = b2f(vec[256 + h * 32 + t]); bs[t] = b2f(vec[512 + h * 32 + t]); }
    __syncthreads();
    int d = t >> 3, e0 = (t & 7) * 4;
    float a0 = 0.f, a1 = 0.f, a2 = 0.f, a3 = 0.f;
    const size_t base_off = ((size_t)b * 4096 + ch * 512) * 256 + h * 32;
    int srow = b * 4096 + ch * 512;
    for (int s0 = 0; s0 < 512; s0 += 64) {
        int m = t >> 2, c0 = (t & 3) * 8;
        float2 st = stats[srow + s0 + m];
        float xv[8];
        if (df) {
            const float4* p = (const float4*)((const float*)x2v + base_off + (size_t)(s0 + m) * 256 + c0);
            float4 f0 = p[0], f1 = p[1];
            xv[0] = f0.x; xv[1] = f0.y; xv[2] = f0.z; xv[3] = f0.w;
            xv[4] = f1.x; xv[5] = f1.y; xv[6] = f1.z; xv[7] = f1.w;
        } else {
            const ushort4* p = (const ushort4*)((const unsigned short*)x2v + base_off + (size_t)(s0 + m) * 256 + c0);
            ushort4 u0 = p[0], u1 = p[1];
            xv[0] = b2f(u0.x); xv[1] = b2f(u0.y); xv[2] = b2f(u0.z); xv[3] = b2f(u0.w);
            xv[4] = b2f(u1.x); xv[5] = b2f(u1.y); xv[6] = b2f(u1.z); xv[7] = b2f(u1.w);
        }
#pragma unroll
        for (int j = 0; j < 8; j++)
            E[m * 33 + c0 + j] = __expf((xv[j] - st.x) * st.y * gs[c0 + j] + bs[c0 + j]);
        __syncthreads();
        if (t < 64) {
            float s = 0.f;
#pragma unroll
            for (int c = 0; c < 32; c++) s += E[t * 33 + c];
            qinv[t] = 1.0f / s;
        }
        __syncthreads();
        {
            float qi = qinv[m];
#pragma unroll
            for (int j = 0; j < 8; j++) Q[m * 33 + c0 + j] = E[m * 33 + c0 + j] * qi;
        }
        __syncthreads();
#pragma unroll 4
        for (int mm = 0; mm < 64; mm++) {
            float qd = Q[mm * 33 + d];
            a0 += qd * E[mm * 33 + e0 + 0];
            a1 += qd * E[mm * 33 + e0 + 1];
            a2 += qd * E[mm * 33 + e0 + 2];
            a3 += qd * E[mm * 33 + e0 + 3];
        }
        __syncthreads();
    }
    float* dst = ctxraw + ((size_t)bh << 10) + (d << 5) + e0;
    atomicAdd(dst + 0, a0);
    atomicAdd(dst + 1, a1);
    atomicAdd(dst + 2, a2);
    atomicAdd(dst + 3, a3);
}

// w2t[b][o][h*32+e] = (1/colsum[e]) * sum_d ctx[d,e]*rw[o,h*32+d];
// colsum[e] = sum_d ctxraw[d,e] (q-softmax rows sum to 1)
__global__ __launch_bounds__(256) void k_w2(const float* __restrict__ ctxraw,
                                            const unsigned short* __restrict__ rwb,
                                            unsigned short* __restrict__ w2t) {
    __shared__ float ctx_s[1024];   // [d][e]
    __shared__ float cinv[32];
    int bh = blockIdx.x;
    int b = bh >> 3, h = bh & 7;
    int t = threadIdx.x;
#pragma unroll
    for (int i = 0; i < 4; i++) ctx_s[t + 256 * i] = ctxraw[((size_t)bh << 10) + t + 256 * i];
    __syncthreads();
    if (t < 32) {
        float s = 0.f;
#pragma unroll
        for (int d = 0; d < 32; d++) s += ctx_s[d * 32 + t];
        cinv[t] = 1.0f / s;
    }
    __syncthreads();
    float w0[32], w1[32];
#pragma unroll
    for (int d = 0; d < 32; d++) {
        w0[d] = b2f(rwb[(size_t)t * 256 + h * 32 + d]);
        w1[d] = b2f(rwb[(size_t)(t + 256) * 256 + h * 32 + d]);
    }
#pragma unroll 4
    for (int e = 0; e < 32; e++) {
        float ci = cinv[e];
        float s0 = 0.f, s1 = 0.f;
#pragma unroll
        for (int d = 0; d < 32; d++) {
            float c = ctx_s[d * 32 + e];
            s0 += c * w0[d];
            s1 += c * w1[d];
        }
        int cidx = h * 32 + e;
        w2t[((size_t)b * 512 + t) * 256 + cidx] = f2b(s0 * ci);
        w2t[((size_t)b * 512 + t + 256) * 256 + cidx] = f2b(s1 * ci);
    }
}

// Fused: GEMM1(x1@W)+bias+LN -> n1 tile in LDS -> GEMM2(n1@w2t^T)+bias+LN(512)+x1 -> out
__global__ __launch_bounds__(256) void k_fused(
    const void* __restrict__ x1v, const unsigned short* __restrict__ wt1,
    const unsigned short* __restrict__ vec, const unsigned short* __restrict__ w2t,
    const int* __restrict__ flag, void* __restrict__ outv) {
    __shared__ unsigned short n1s[64 * 264];   // 33792 B
    __shared__ unsigned short pool[12800];     // 25600 B
    unsigned short* As1 = pool;                // [64][40]
    unsigned short* Bs1 = pool + 2560;         // [256][40]
    unsigned short* Bs2 = pool;                // [256][40]
    const int df = *flag;
    const int t = threadIdx.x;
    const int lane = t & 63, w = t >> 6;
    const int l15 = lane & 15, quad = lane >> 4;
    const int row0 = blockIdx.x * 64;
    const unsigned short* wb = w2t + (size_t)(row0 >> 12) * (512 * 256);
    const int mrow = (w << 4) + l15;
    const int k8 = quad * 8;
    const int stg_m = t >> 2, stg_k = (t & 3) * 8;

    // ---------- phase 1: GEMM1 (K=512, N=256) ----------
    f32x4 acc1[16];
#pragma unroll
    for (int i = 0; i < 16; i++) acc1[i] = (f32x4){0.f, 0.f, 0.f, 0.f};
    for (int k0 = 0; k0 < 512; k0 += 32) {
        if (df) {
            const float* xf = (const float*)x1v + (size_t)(row0 + stg_m) * 512 + k0 + stg_k;
            float4 f0 = *(const float4*)xf;
            float4 f1 = *(const float4*)(xf + 4);
            ushort4 lo, hi;
            lo.x = f2b(f0.x); lo.y = f2b(f0.y); lo.z = f2b(f0.z); lo.w = f2b(f0.w);
            hi.x = f2b(f1.x); hi.y = f2b(f1.y); hi.z = f2b(f1.z); hi.w = f2b(f1.w);
            *(ushort4*)(As1 + stg_m * 40 + stg_k) = lo;
            *(ushort4*)(As1 + stg_m * 40 + stg_k + 4) = hi;
        } else {
            *(uint4*)(As1 + stg_m * 40 + stg_k) =
                *(const uint4*)((const unsigned short*)x1v + (size_t)(row0 + stg_m) * 512 + k0 + stg_k);
        }
#pragma unroll
        for (int p = 0; p < 4; p++) {
            int n = stg_m + p * 64;
            *(uint4*)(Bs1 + n * 40 + stg_k) =
                *(const uint4*)(wt1 + (size_t)n * 512 + k0 + stg_k);
        }
        __syncthreads();
        bf16x8 a = *(const bf16x8*)(As1 + mrow * 40 + k8);
#pragma unroll
        for (int cb = 0; cb < 16; cb++) {
            bf16x8 bf = *(const bf16x8*)(Bs1 + ((cb << 4) + l15) * 40 + k8);
            acc1[cb] = __builtin_amdgcn_mfma_f32_16x16x32_bf16(a, bf, acc1[cb], 0, 0, 0);
        }
        __syncthreads();
    }
    // bias + LN(256) -> n1 tile (bf16) in LDS
#pragma unroll
    for (int cb = 0; cb < 16; cb++) {
        float bc = b2f(vec[(cb << 4) + l15]);          // lb
#pragma unroll
        for (int r = 0; r < 4; r++) acc1[cb][r] += bc;
    }
    float mean_[4], rstd_[4];
#pragma unroll
    for (int r = 0; r < 4; r++) {
        float s = 0.f, q = 0.f;
#pragma unroll
        for (int cb = 0; cb < 16; cb++) { float v = acc1[cb][r]; s += v; q += v * v; }
#pragma unroll
        for (int msk = 1; msk < 16; msk <<= 1) {
            s += __shfl_xor(s, msk, 64);
            q += __shfl_xor(q, msk, 64);
        }
        float mn = s * (1.0f / 256.0f);
        mean_[r] = mn;
        rstd_[r] = rsqrtf(q * (1.0f / 256.0f) - mn * mn + EPS);
    }
#pragma unroll
    for (int cb = 0; cb < 16; cb++) {
        int col = (cb << 4) + l15;
        float gg = b2f(vec[256 + col]), bbv = b2f(vec[512 + col]);   // g1, b1
#pragma unroll
        for (int r = 0; r < 4; r++) {
            int rr = (w << 4) + (quad << 2) + r;
            n1s[rr * 264 + col] = f2b((acc1[cb][r] - mean_[r]) * rstd_[r] * gg + bbv);
        }
    }
    __syncthreads();

    // ---------- phase 2: GEMM2 (K=256, N=512 in two halves) ----------
    f32x4 acc2[2][16];
#pragma unroll
    for (int hf = 0; hf < 2; hf++)
#pragma unroll
        for (int i = 0; i < 16; i++) acc2[hf][i] = (f32x4){0.f, 0.f, 0.f, 0.f};
    for (int hf = 0; hf < 2; hf++) {
        const unsigned short* wh = wb + (size_t)hf * 256 * 256;
        for (int k0 = 0; k0 < 256; k0 += 32) {
#pragma unroll
            for (int p = 0; p < 4; p++) {
                int n = stg_m + p * 64;
                *(uint4*)(Bs2 + n * 40 + stg_k) =
                    *(const uint4*)(wh + (size_t)n * 256 + k0 + stg_k);
            }
            __syncthreads();
            bf16x8 a = *(const bf16x8*)(n1s + mrow * 264 + k0 + k8);
#pragma unroll
            for (int cb = 0; cb < 16; cb++) {
                bf16x8 bf = *(const bf16x8*)(Bs2 + ((cb << 4) + l15) * 40 + k8);
                acc2[hf][cb] = __builtin_amdgcn_mfma_f32_16x16x32_bf16(a, bf, acc2[hf][cb], 0, 0, 0);
            }
            __syncthreads();
        }
    }
    // bias + LN(512) + x1 + store
#pragma unroll
    for (int hf = 0; hf < 2; hf++)
#pragma unroll
        for (int cb = 0; cb < 16; cb++) {
            float bc = b2f(vec[768 + hf * 256 + (cb << 4) + l15]);   // rb
#pragma unroll
            for (int r = 0; r < 4; r++) acc2[hf][cb][r] += bc;
        }
#pragma unroll
    for (int r = 0; r < 4; r++) {
        float s = 0.f, q = 0.f;
#pragma unroll
        for (int hf = 0; hf < 2; hf++)
#pragma unroll
            for (int cb = 0; cb < 16; cb++) { float v = acc2[hf][cb][r]; s += v; q += v * v; }
#pragma unroll
        for (int msk = 1; msk < 16; msk <<= 1) {
            s += __shfl_xor(s, msk, 64);
            q += __shfl_xor(q, msk, 64);
        }
        float mn = s * (1.0f / 512.0f);
        mean_[r] = mn;
        rstd_[r] = rsqrtf(q * (1.0f / 512.0f) - mn * mn + EPS);
    }
#pragma unroll
    for (int hf = 0; hf < 2; hf++)
#pragma unroll
        for (int cb = 0; cb < 16; cb++) {
            int col = hf * 256 + (cb << 4) + l15;
            float gg = b2f(vec[1280 + col]), bbv = b2f(vec[1792 + col]);  // ga, ba
#pragma unroll
            for (int r = 0; r < 4; r++) {
                size_t idx = (size_t)(row0 + (w << 4) + (quad << 2) + r) * 512 + col;
                float xadd = df ? ((const float*)x1v)[idx]
                               : b2f(((const unsigned short*)x1v)[idx]);
                float v = (acc2[hf][cb][r] - mean_[r]) * rstd_[r] * gg + bbv + xadd;
                if (df) ((float*)outv)[idx] = v;
                else    ((unsigned short*)outv)[idx] = f2b(v);
            }
        }
}

extern "C" void kernel_launch(void* const* d_in, const int* in_sizes, int n_in,
                              void* d_out, int out_size, void* d_ws, size_t ws_size,
                              hipStream_t stream) {
    const void* x1 = d_in[0];
    const void* x2 = d_in[1];
    const void* lw = d_in[2];
    const void* lb = d_in[3];
    const void* g1 = d_in[4];
    const void* b1 = d_in[5];
    const void* rw = d_in[6];
    const void* rb = d_in[7];
    const void* ga = d_in[8];
    const void* ba = d_in[9];

    char* ws = (char*)d_ws;
    float*          ctxr  = (float*)(ws);                       // 256 KB
    float2*         stats = (float2*)(ws + 262144);             // 256 KB
    unsigned short* wt1   = (unsigned short*)(ws + 524288);     // 256 KB
    unsigned short* rwb   = (unsigned short*)(ws + 786432);     // 256 KB
    unsigned short* vec   = (unsigned short*)(ws + 1048576);    // 4.5 KB
    int*            flag  = (int*)(ws + 1056768);               // 4 B
    unsigned short* w2t   = (unsigned short*)(ws + 1064960);    // 2 MB (total ~3.1 MB)

    k_detect<<<dim3(1), dim3(64), 0, stream>>>(lw, flag);
    k_zero<<<dim3(256), dim3(256), 0, stream>>>(ctxr, 65536);
    k_params<<<dim3(1033), dim3(256), 0, stream>>>(lw, rw, lb, g1, b1, rb, ga, ba,
                                                   flag, wt1, rwb, vec);
    k_stats<<<dim3(8192), dim3(256), 0, stream>>>(x2, flag, stats);
    k_ctx<<<dim3(512), dim3(256), 0, stream>>>(x2, stats, vec, flag, ctxr);
    k_w2<<<dim3(64), dim3(256), 0, stream>>>(ctxr, rwb, w2t);
    k_fused<<<dim3(512), dim3(256), 0, stream>>>(x1, wt1, vec, w2t, flag, d_out);
}

// Round 4
// 243.951 us; speedup vs baseline: 1.4358x; 1.4358x over previous
//
#include <hip/hip_runtime.h>
#include <stdint.h>

typedef __bf16 bf16x8 __attribute__((ext_vector_type(8)));
typedef float f32x4 __attribute__((ext_vector_type(4)));

#define EPS 1e-5f

__device__ __forceinline__ float b2f(unsigned short u) {
    union { unsigned int i; float f; } c; c.i = ((unsigned int)u) << 16; return c.f;
}
__device__ __forceinline__ unsigned short f2b(float f) {
    union { float f; unsigned int i; } c; c.f = f;
    unsigned int i = c.i;
    return (unsigned short)((i + 0x7FFFu + ((i >> 16) & 1u)) >> 16);
}

__global__ void k_zero(float* __restrict__ p, int n) {
    int i = blockIdx.x * 256 + threadIdx.x;
    if (i < n) p[i] = 0.0f;
}

// Canonicalize params to bf16: wt1 = lw^T [256][512]; rwb = rw [512][256];
// vec = {lb(256), g1(256), b1(256), rb(512), ga(512), ba(512)}
__global__ void k_params(const float* __restrict__ lw, const float* __restrict__ rw,
                         const float* __restrict__ lb, const float* __restrict__ g1,
                         const float* __restrict__ b1, const float* __restrict__ rb,
                         const float* __restrict__ ga, const float* __restrict__ ba,
                         unsigned short* __restrict__ wt1,
                         unsigned short* __restrict__ rwb,
                         unsigned short* __restrict__ vec) {
    int gid = blockIdx.x * 256 + threadIdx.x;
    if (gid < 131072) {
        int k = gid >> 8, n = gid & 255;
        wt1[n * 512 + k] = f2b(lw[gid]);
    } else if (gid < 262144) {
        int j = gid - 131072;
        rwb[j] = f2b(rw[j]);
    } else if (gid < 264448) {
        int j = gid - 262144;
        if (j < 256)       vec[j] = f2b(lb[j]);
        else if (j < 512)  vec[j] = f2b(g1[j - 256]);
        else if (j < 768)  vec[j] = f2b(b1[j - 512]);
        else if (j < 1280) vec[j] = f2b(rb[j - 768]);
        else if (j < 1792) vec[j] = f2b(ga[j - 1280]);
        else               vec[j] = f2b(ba[j - 1792]);
    }
}

// per-row LN stats of x2 (row length 256); one wave per row
__global__ __launch_bounds__(256) void k_stats(const float* __restrict__ x2,
                                               float2* __restrict__ stats) {
    int t = threadIdx.x, lane = t & 63, w = t >> 6;
    size_t row = (size_t)blockIdx.x * 4 + w;
    float4 f = *(const float4*)(x2 + row * 256 + lane * 4);
    float s = f.x + f.y + f.z + f.w;
    float q = f.x * f.x + f.y * f.y + f.z * f.z + f.w * f.w;
#pragma unroll
    for (int msk = 1; msk < 64; msk <<= 1) {
        s += __shfl_xor(s, msk, 64);
        q += __shfl_xor(q, msk, 64);
    }
    float mn = s * (1.0f / 256.0f);
    float rstd = rsqrtf(q * (1.0f / 256.0f) - mn * mn + EPS);
    if (lane == 0) stats[row] = make_float2(mn, rstd);
}

// ctxraw[b,h,d,e] = sum_m q[d,m]*E[e,m], n2=LN(x2) on the fly.
// grid 512 = (b,h)(64) x chunk(8 of 512 tokens); 256 thr
__global__ __launch_bounds__(256) void k_ctx(const float* __restrict__ x2,
                                             const float2* __restrict__ stats,
                                             const unsigned short* __restrict__ vec,
                                             float* __restrict__ ctxraw) {
    __shared__ float E[64 * 36];
    __shared__ float Q[64 * 36];
    __shared__ float gs[32], bs[32];
    int bh = blockIdx.x >> 3;
    int b = bh >> 3, h = bh & 7;
    int ch = blockIdx.x & 7;
    int t = threadIdx.x;
    if (t < 32) { gs[t] = b2f(vec[256 + h * 32 + t]); bs[t] = b2f(vec[512 + h * 32 + t]); }
    __syncthreads();
    int d = t >> 3, e0 = (t & 7) * 4;
    float a0 = 0.f, a1 = 0.f, a2 = 0.f, a3 = 0.f;
    const float* base = x2 + ((size_t)b * 4096 + ch * 512) * 256 + h * 32;
    int srow = b * 4096 + ch * 512;
    const int m = t >> 2, c0 = (t & 3) * 8;
    for (int s0 = 0; s0 < 512; s0 += 64) {
        float2 st = stats[srow + s0 + m];
        const float4* p = (const float4*)(base + (size_t)(s0 + m) * 256 + c0);
        float4 f0 = p[0], f1 = p[1];
        float ev[8];
        ev[0] = __expf((f0.x - st.x) * st.y * gs[c0 + 0] + bs[c0 + 0]);
        ev[1] = __expf((f0.y - st.x) * st.y * gs[c0 + 1] + bs[c0 + 1]);
        ev[2] = __expf((f0.z - st.x) * st.y * gs[c0 + 2] + bs[c0 + 2]);
        ev[3] = __expf((f0.w - st.x) * st.y * gs[c0 + 3] + bs[c0 + 3]);
        ev[4] = __expf((f1.x - st.x) * st.y * gs[c0 + 4] + bs[c0 + 4]);
        ev[5] = __expf((f1.y - st.x) * st.y * gs[c0 + 5] + bs[c0 + 5]);
        ev[6] = __expf((f1.z - st.x) * st.y * gs[c0 + 6] + bs[c0 + 6]);
        ev[7] = __expf((f1.w - st.x) * st.y * gs[c0 + 7] + bs[c0 + 7]);
        float ps = ev[0] + ev[1] + ev[2] + ev[3] + ev[4] + ev[5] + ev[6] + ev[7];
        ps += __shfl_xor(ps, 1, 64);
        ps += __shfl_xor(ps, 2, 64);     // 4 threads of token m are lanes differing in bits 0-1
        float qi = 1.0f / ps;
        *(float4*)(E + m * 36 + c0)     = make_float4(ev[0], ev[1], ev[2], ev[3]);
        *(float4*)(E + m * 36 + c0 + 4) = make_float4(ev[4], ev[5], ev[6], ev[7]);
        *(float4*)(Q + m * 36 + c0)     = make_float4(ev[0]*qi, ev[1]*qi, ev[2]*qi, ev[3]*qi);
        *(float4*)(Q + m * 36 + c0 + 4) = make_float4(ev[4]*qi, ev[5]*qi, ev[6]*qi, ev[7]*qi);
        __syncthreads();
#pragma unroll 4
        for (int mm = 0; mm < 64; mm++) {
            float qd = Q[mm * 36 + d];
            float4 e4 = *(const float4*)(E + mm * 36 + e0);
            a0 += qd * e4.x; a1 += qd * e4.y; a2 += qd * e4.z; a3 += qd * e4.w;
        }
        __syncthreads();
    }
    float* dst = ctxraw + ((size_t)bh << 10) + (d << 5) + e0;
    atomicAdd(dst + 0, a0);
    atomicAdd(dst + 1, a1);
    atomicAdd(dst + 2, a2);
    atomicAdd(dst + 3, a3);
}

// w2t[b][o][h*32+e] = (1/colsum[e]) * sum_d ctx[d,e]*rw[o,h*32+d]
// grid 512 = (b(8), h(8), osplit(8)); thread: o = os*64 + t>>2, e-range (t&3)*8..+8
__global__ __launch_bounds__(256) void k_w2(const float* __restrict__ ctxraw,
                                            const unsigned short* __restrict__ rwb,
                                            unsigned short* __restrict__ w2t) {
    __shared__ float ctx_s[1024];   // [d][e]
    __shared__ float cinv[32];
    int blk = blockIdx.x;
    int b = blk >> 6, h = (blk >> 3) & 7, os = blk & 7;
    int bh = b * 8 + h;
    int t = threadIdx.x;
#pragma unroll
    for (int i = 0; i < 4; i++) ctx_s[t + 256 * i] = ctxraw[((size_t)bh << 10) + t + 256 * i];
    __syncthreads();
    if (t < 32) {
        float s = 0.f;
#pragma unroll
        for (int d = 0; d < 32; d++) s += ctx_s[d * 32 + t];
        cinv[t] = 1.0f / s;
    }
    __syncthreads();
    int o = os * 64 + (t >> 2);
    int e0 = (t & 3) * 8;
    // load 32 bf16 of reproj row slice
    float wv[32];
    const uint4* wp = (const uint4*)(rwb + (size_t)o * 256 + h * 32);
#pragma unroll
    for (int qd = 0; qd < 4; qd++) {
        uint4 u = wp[qd];
        unsigned int uu[4] = {u.x, u.y, u.z, u.w};
#pragma unroll
        for (int j = 0; j < 4; j++) {
            wv[qd * 8 + j * 2]     = b2f((unsigned short)(uu[j] & 0xFFFFu));
            wv[qd * 8 + j * 2 + 1] = b2f((unsigned short)(uu[j] >> 16));
        }
    }
    float s[8];
#pragma unroll
    for (int j = 0; j < 8; j++) s[j] = 0.f;
#pragma unroll 8
    for (int d = 0; d < 32; d++) {
        float w = wv[d];
#pragma unroll
        for (int j = 0; j < 8; j++) s[j] += ctx_s[d * 32 + e0 + j] * w;
    }
    ushort4 o4a, o4b;
    o4a.x = f2b(s[0] * cinv[e0 + 0]); o4a.y = f2b(s[1] * cinv[e0 + 1]);
    o4a.z = f2b(s[2] * cinv[e0 + 2]); o4a.w = f2b(s[3] * cinv[e0 + 3]);
    o4b.x = f2b(s[4] * cinv[e0 + 4]); o4b.y = f2b(s[5] * cinv[e0 + 5]);
    o4b.z = f2b(s[6] * cinv[e0 + 6]); o4b.w = f2b(s[7] * cinv[e0 + 7]);
    unsigned short* dst = w2t + ((size_t)b * 512 + o) * 256 + h * 32 + e0;
    *(ushort4*)dst = o4a;
    *(ushort4*)(dst + 4) = o4b;
}

// GEMM1 + LN: n1 = LN(x1 @ W + lb) -> bf16 [32768][256]
// 256 thr / 4 waves, tile 64x256, BK=32
__global__ __launch_bounds__(256) void k_gemm1(
    const float* __restrict__ x1, const unsigned short* __restrict__ wt1,
    const unsigned short* __restrict__ vec, unsigned short* __restrict__ n1) {
    __shared__ unsigned short pool[16896];     // 33792 B: staging (25600) / n1 repack (33792)
    unsigned short* As = pool;                 // [64][40]
    unsigned short* Bs = pool + 2560;          // [256][40]
    unsigned short* n1s = pool;                // [64][264]
    const int t = threadIdx.x;
    const int lane = t & 63, w = t >> 6;
    const int l15 = lane & 15, quad = lane >> 4;
    const int row0 = blockIdx.x * 64;
    const int mrow = (w << 4) + l15;
    const int k8 = quad * 8;
    const int stg_m = t >> 2, stg_k = (t & 3) * 8;

    f32x4 acc[16];
#pragma unroll
    for (int i = 0; i < 16; i++) acc[i] = (f32x4){0.f, 0.f, 0.f, 0.f};

    for (int k0 = 0; k0 < 512; k0 += 32) {
        {
            const float* xf = x1 + (size_t)(row0 + stg_m) * 512 + k0 + stg_k;
            float4 f0 = *(const float4*)xf;
            float4 f1 = *(const float4*)(xf + 4);
            ushort4 lo, hi;
            lo.x = f2b(f0.x); lo.y = f2b(f0.y); lo.z = f2b(f0.z); lo.w = f2b(f0.w);
            hi.x = f2b(f1.x); hi.y = f2b(f1.y); hi.z = f2b(f1.z); hi.w = f2b(f1.w);
            *(ushort4*)(As + stg_m * 40 + stg_k) = lo;
            *(ushort4*)(As + stg_m * 40 + stg_k + 4) = hi;
        }
#pragma unroll
        for (int p = 0; p < 4; p++) {
            int n = stg_m + p * 64;
            *(uint4*)(Bs + n * 40 + stg_k) =
                *(const uint4*)(wt1 + (size_t)n * 512 + k0 + stg_k);
        }
        __syncthreads();
        bf16x8 a = *(const bf16x8*)(As + mrow * 40 + k8);
#pragma unroll
        for (int cb = 0; cb < 16; cb++) {
            bf16x8 bf = *(const bf16x8*)(Bs + ((cb << 4) + l15) * 40 + k8);
            acc[cb] = __builtin_amdgcn_mfma_f32_16x16x32_bf16(a, bf, acc[cb], 0, 0, 0);
        }
        __syncthreads();
    }
    // bias + LN(256)
#pragma unroll
    for (int cb = 0; cb < 16; cb++) {
        float bc = b2f(vec[(cb << 4) + l15]);
#pragma unroll
        for (int r = 0; r < 4; r++) acc[cb][r] += bc;
    }
    float mean_[4], rstd_[4];
#pragma unroll
    for (int r = 0; r < 4; r++) {
        float s = 0.f, q = 0.f;
#pragma unroll
        for (int cb = 0; cb < 16; cb++) { float v = acc[cb][r]; s += v; q += v * v; }
#pragma unroll
        for (int msk = 1; msk < 16; msk <<= 1) {
            s += __shfl_xor(s, msk, 64);
            q += __shfl_xor(q, msk, 64);
        }
        float mn = s * (1.0f / 256.0f);
        mean_[r] = mn;
        rstd_[r] = rsqrtf(q * (1.0f / 256.0f) - mn * mn + EPS);
    }
#pragma unroll
    for (int cb = 0; cb < 16; cb++) {
        int col = (cb << 4) + l15;
        float gg = b2f(vec[256 + col]), bbv = b2f(vec[512 + col]);
#pragma unroll
        for (int r = 0; r < 4; r++) {
            int rr = (w << 4) + (quad << 2) + r;
            n1s[rr * 264 + col] = f2b((acc[cb][r] - mean_[r]) * rstd_[r] * gg + bbv);
        }
    }
    __syncthreads();
    // coalesced store: thread t: row t>>2, 8 chunks of 8 halfwords
    {
        int row = t >> 2;
        unsigned short* dst = n1 + (size_t)(row0 + row) * 256;
        const unsigned short* src = n1s + row * 264;
#pragma unroll
        for (int j = 0; j < 8; j++) {
            int chunk = (t & 3) * 8 + j;
            *(uint4*)(dst + chunk * 8) = *(const uint4*)(src + chunk * 8);
        }
    }
}

// GEMM2 + bias + LN(512) + residual: out = LN(n1 @ w2t^T + rb)*ga + ba + x1
// 512 thr / 8 waves; tile 64 rows x 512 cols; wave w: rows (w&3)*16.., col half w>>2
__global__ __launch_bounds__(512) void k_gemm2(
    const unsigned short* __restrict__ n1, const unsigned short* __restrict__ w2t,
    const unsigned short* __restrict__ vec, const float* __restrict__ x1,
    float* __restrict__ out) {
    __shared__ unsigned short As[64 * 40];     // 5120 B
    __shared__ unsigned short Bs[512 * 40];    // 40960 B
    __shared__ float2 red[2][64];              // 1024 B
    const int t = threadIdx.x;
    const int lane = t & 63, w = t >> 6;
    const int l15 = lane & 15, quad = lane >> 4;
    const int hf = w >> 2, wr = w & 3;
    const int row0 = blockIdx.x * 64;
    const unsigned short* wb = w2t + (size_t)(row0 >> 12) * (512 * 256);
    const int mrow = (wr << 4) + l15;
    const int k8 = quad * 8;

    f32x4 acc[16];
#pragma unroll
    for (int i = 0; i < 16; i++) acc[i] = (f32x4){0.f, 0.f, 0.f, 0.f};

    for (int k0 = 0; k0 < 256; k0 += 32) {
        if (t < 256) {
            int m = t >> 2, kc = (t & 3) * 8;
            *(uint4*)(As + m * 40 + kc) =
                *(const uint4*)(n1 + (size_t)(row0 + m) * 256 + k0 + kc);
        }
#pragma unroll
        for (int p = 0; p < 4; p++) {
            int n = (t >> 2) + p * 128, kc = (t & 3) * 8;
            *(uint4*)(Bs + n * 40 + kc) =
                *(const uint4*)(wb + (size_t)n * 256 + k0 + kc);
        }
        __syncthreads();
        bf16x8 a = *(const bf16x8*)(As + mrow * 40 + k8);
#pragma unroll
        for (int cb = 0; cb < 16; cb++) {
            int ncol = (hf << 8) + (cb << 4) + l15;
            bf16x8 bf = *(const bf16x8*)(Bs + ncol * 40 + k8);
            acc[cb] = __builtin_amdgcn_mfma_f32_16x16x32_bf16(a, bf, acc[cb], 0, 0, 0);
        }
        __syncthreads();
    }
    // + rb
#pragma unroll
    for (int cb = 0; cb < 16; cb++) {
        float bc = b2f(vec[768 + (hf << 8) + (cb << 4) + l15]);
#pragma unroll
        for (int r = 0; r < 4; r++) acc[cb][r] += bc;
    }
    // half-row sums -> LDS -> combine
#pragma unroll
    for (int r = 0; r < 4; r++) {
        float s = 0.f, q = 0.f;
#pragma unroll
        for (int cb = 0; cb < 16; cb++) { float v = acc[cb][r]; s += v; q += v * v; }
#pragma unroll
        for (int msk = 1; msk < 16; msk <<= 1) {
            s += __shfl_xor(s, msk, 64);
            q += __shfl_xor(q, msk, 64);
        }
        if (l15 == 0) red[hf][(wr << 4) + (quad << 2) + r] = make_float2(s, q);
    }
    __syncthreads();
    float mean_[4], rstd_[4];
#pragma unroll
    for (int r = 0; r < 4; r++) {
        int rl = (wr << 4) + (quad << 2) + r;
        float2 cA = red[0][rl], cB = red[1][rl];
        float s = cA.x + cB.x, q = cA.y + cB.y;
        float mn = s * (1.0f / 512.0f);
        mean_[r] = mn;
        rstd_[r] = rsqrtf(q * (1.0f / 512.0f) - mn * mn + EPS);
    }
#pragma unroll
    for (int cb = 0; cb < 16; cb++) {
        int col = (hf << 8) + (cb << 4) + l15;
        float gg = b2f(vec[1280 + col]), bbv = b2f(vec[1792 + col]);
#pragma unroll
        for (int r = 0; r < 4; r++) {
            size_t idx = (size_t)(row0 + (wr << 4) + (quad << 2) + r) * 512 + col;
            out[idx] = (acc[cb][r] - mean_[r]) * rstd_[r] * gg + bbv + x1[idx];
        }
    }
}

extern "C" void kernel_launch(void* const* d_in, const int* in_sizes, int n_in,
                              void* d_out, int out_size, void* d_ws, size_t ws_size,
                              hipStream_t stream) {
    const float* x1 = (const float*)d_in[0];
    const float* x2 = (const float*)d_in[1];
    const float* lw = (const float*)d_in[2];
    const float* lb = (const float*)d_in[3];
    const float* g1 = (const float*)d_in[4];
    const float* b1 = (const float*)d_in[5];
    const float* rw = (const float*)d_in[6];
    const float* rb = (const float*)d_in[7];
    const float* ga = (const float*)d_in[8];
    const float* ba = (const float*)d_in[9];
    float* out = (float*)d_out;

    char* ws = (char*)d_ws;
    float*          ctxr  = (float*)(ws);                       // 256 KB
    float2*         stats = (float2*)(ws + 262144);             // 256 KB
    unsigned short* wt1   = (unsigned short*)(ws + 524288);     // 256 KB
    unsigned short* rwb   = (unsigned short*)(ws + 786432);     // 256 KB
    unsigned short* vec   = (unsigned short*)(ws + 1048576);    // 4.5 KB
    unsigned short* w2t   = (unsigned short*)(ws + 1064960);    // 2 MB
    unsigned short* n1    = (unsigned short*)(ws + 4194304);    // 16 MB (total ~20 MB)

    k_zero<<<dim3(256), dim3(256), 0, stream>>>(ctxr, 65536);
    k_params<<<dim3(1033), dim3(256), 0, stream>>>(lw, rw, lb, g1, b1, rb, ga, ba,
                                                   wt1, rwb, vec);
    k_stats<<<dim3(8192), dim3(256), 0, stream>>>(x2, stats);
    k_ctx<<<dim3(512), dim3(256), 0, stream>>>(x2, stats, vec, ctxr);
    k_w2<<<dim3(512), dim3(256), 0, stream>>>(ctxr, rwb, w2t);
    k_gemm1<<<dim3(512), dim3(256), 0, stream>>>(x1, wt1, vec, n1);
    k_gemm2<<<dim3(512), dim3(512), 0, stream>>>(n1, w2t, vec, x1, out);
}